// Round 12
// baseline (229.502 us; speedup 1.0000x reference)
//
#include <hip/hip_runtime.h>
#include <hip/hip_bf16.h>

// LightGCN propagation: x = concat(user,item) [150000,64] f32;
// acc = x; 3x { x = A@x (COO spmm, E=1.2M); acc += x }; out = acc/4.
//
// Round 12 = round 11 (int-fixed-point bucket-LDS spmm, scatter2 DELETED)
// + round 7's staged-coalesced s1 write-out, ported to shift 7:
//  1) memset cursor1 (1172 x 4B)
//  2) s1_convert (role-split grid): LDS-rank edges per bucket (row>>7),
//     reserve via atomicAdd(cursor1[b]); records sorted bucket-contiguously
//     into LDS staging (scan of 1184 counters, 3/thread), then written out
//     coalesced (was: scattered 8B stores, 57MB lines for 28.8MB useful,
//     s1=44us). + x0 fp32->fp16 staging.
//  3-5) spmm_bucket x3 (verified round 11, <=42us/layer): block = bucket
//     (128 rows), 512 thr, LDS acc 128x65 INT via native ds_add_u32.
//     SCALE=2^20 fixed point: quant 5e-7/term, invisible vs 2.4e-4 fp16
//     floor. Layer 3 fuses out = 0.25*(x0h+x1+x2+acc).
//
// POST-MORTEM LOG:
//  - prior session r6: nt-STORES on Xout REGRESSED spmm: evicts L2 lines
//    next layer's gathers need.
//  - round 2: per-edge GLOBAL atomicAdd(+return) = 331us. NEVER.
//  - round 5: FP32 LDS atomicAdd = 435us/layer (CAS retry). Int LDS
//    atomicAdd is native ds_add — round 11 proved it: <=42us/layer.
//  - round 6: degree-sorted slots REGRESSED: spmm is GATHER-bound
//    (X=19.2MB vs 4MB/XCD L2), not lockstep-issue-bound.
//  - round 9: packed cw + nt-loads REGRESSED: spmm FETCH -8MB, duration
//    UNCHANGED -> gather-LATENCY bound.
//  - round 10: quarter-split scatter2 +8us: scan amplification.
//  - round 11 (218.3us): bucket-int spmm OK but s1 reverted to unstaged
//    (44us, 2x write amplification). This round re-stages it.
//  - round 7 (old best 214.1us): staged-coalesced writes at shift 9.

#define EMB 64
#define BUCKET_SHIFT 7
#define BROWS (1 << BUCKET_SHIFT)    // 128 rows per bucket
#define LROW 65                      // LDS row stride (65 = 1 mod 32)
#define NBUCK_PAD 1184
#define S1_CHUNK 2048
#define BCAP 1408                    // Poisson(1024): +12 sigma headroom
#define ACC_SCALE 1048576.0f         // 2^20 fixed-point scale
#define ACC_INV (1.0f / 1048576.0f)

typedef _Float16 h8 __attribute__((ext_vector_type(8)));
typedef float f4 __attribute__((ext_vector_type(4)));

union H8U { h8 v; _Float16 e[8]; };

// ---- fused scatter1 + fp32->fp16 convert (role-split grid) ----
// Records staged bucket-contiguously in LDS, written out coalesced.
__global__ void s1_convert(const int* __restrict__ row, const int* __restrict__ col,
                           const float* __restrict__ w, int* __restrict__ cursor1,
                           int2* __restrict__ tmp,
                           const float* __restrict__ ue, const float* __restrict__ ie,
                           h8* __restrict__ X0h, int nu_elems, int total8,
                           int E, int s1Blocks) {
    int t = threadIdx.x;
    if ((int)blockIdx.x < s1Blocks) {
        __shared__ int lcount[NBUCK_PAD];     // 4.7 KB
        __shared__ int lbase[NBUCK_PAD];      // 4.7 KB
        __shared__ int lexcl[NBUCK_PAD];      // 4.7 KB
        __shared__ int2 staged[S1_CHUNK];     // 16 KB
        __shared__ short sbkt[S1_CHUNK];      // 4 KB
        __shared__ int swS[8];
        int c0 = blockIdx.x * S1_CHUNK;
        int chunk_valid = E - c0;
        if (chunk_valid > S1_CHUNK) chunk_valid = S1_CHUNK;
        for (int i = t; i < NBUCK_PAD; i += 512) lcount[i] = 0;
        __syncthreads();
        int pkc[S1_CHUNK / 512];   // (b<<12)|rank  (rank < ~16 at shift 7)
        int cc[S1_CHUNK / 512];
        int rr[S1_CHUNK / 512];
        float ww[S1_CHUNK / 512];
        #pragma unroll
        for (int i = 0; i < S1_CHUNK / 512; i++) {
            int e = c0 + i * 512 + t;
            pkc[i] = -1;
            if (e < E) {
                int r = row[e];
                int b = r >> BUCKET_SHIFT;
                int rank = atomicAdd(&lcount[b], 1);
                pkc[i] = (b << 12) | rank;
                cc[i] = col[e];
                rr[i] = r & (BROWS - 1);
                ww[i] = w[e];
            }
        }
        __syncthreads();
        // global reservation + exclusive scan of 1184 counters (3/thread)
        int lane = t & 63, wave = t >> 6;
        int b0 = t * 3;
        int c0v = (b0     < NBUCK_PAD) ? lcount[b0]     : 0;
        int c1v = (b0 + 1 < NBUCK_PAD) ? lcount[b0 + 1] : 0;
        int c2v = (b0 + 2 < NBUCK_PAD) ? lcount[b0 + 2] : 0;
        if (b0     < NBUCK_PAD && c0v) lbase[b0]     = atomicAdd(&cursor1[b0],     c0v);
        if (b0 + 1 < NBUCK_PAD && c1v) lbase[b0 + 1] = atomicAdd(&cursor1[b0 + 1], c1v);
        if (b0 + 2 < NBUCK_PAD && c2v) lbase[b0 + 2] = atomicAdd(&cursor1[b0 + 2], c2v);
        int tsum = c0v + c1v + c2v;
        int s = tsum;
        #pragma unroll
        for (int off = 1; off < 64; off <<= 1) {
            int tt = __shfl_up(s, off, 64);
            if (lane >= off) s += tt;
        }
        if (lane == 63) swS[wave] = s;
        __syncthreads();
        {
            int woff = 0;
            for (int wv_ = 0; wv_ < wave; wv_++) woff += swS[wv_];
            int texcl = woff + s - tsum;
            if (b0     < NBUCK_PAD) lexcl[b0]     = texcl;
            if (b0 + 1 < NBUCK_PAD) lexcl[b0 + 1] = texcl + c0v;
            if (b0 + 2 < NBUCK_PAD) lexcl[b0 + 2] = texcl + c0v + c1v;
        }
        __syncthreads();
        // place bucket-sorted into LDS staging
        #pragma unroll
        for (int i = 0; i < S1_CHUNK / 512; i++) {
            if (pkc[i] >= 0) {
                int b = pkc[i] >> 12;
                int si = lexcl[b] + (pkc[i] & 4095);
                staged[si] = make_int2((cc[i] << BUCKET_SHIFT) | rr[i],
                                       __float_as_int(ww[i]));
                sbkt[si] = (short)b;
            }
        }
        __syncthreads();
        // coalesced write-out: consecutive i in a bucket-run -> consecutive tmp
        for (int i = t; i < chunk_valid; i += 512) {
            int b = sbkt[i];
            int pos = lbase[b] + (i - lexcl[b]);
            if (pos < BCAP)   // overflow guard (never triggers at +12 sigma)
                tmp[(size_t)b * BCAP + pos] = staged[i];
        }
    } else {
        int g = (blockIdx.x - s1Blocks) * 512 + t;
        if (g >= total8) return;
        int base = g << 3;
        const f4* src = (const f4*)((base < nu_elems) ? (ue + base)
                                                      : (ie + (base - nu_elems)));
        f4 a = src[0], b = src[1];
        h8 o;
        o[0] = (_Float16)a.x; o[1] = (_Float16)a.y; o[2] = (_Float16)a.z; o[3] = (_Float16)a.w;
        o[4] = (_Float16)b.x; o[5] = (_Float16)b.y; o[6] = (_Float16)b.z; o[7] = (_Float16)b.w;
        X0h[g] = o;
    }
}

// ---- spmm: bucket-per-block, INT LDS accumulate (native ds_add) ----
// (verified round 11, unchanged) LAST fuses out = 0.25*(x0h+x1+x2+acc)
template <bool LAST>
__global__ __launch_bounds__(512) void spmm_bucket(
        const int* __restrict__ cursor1, const int2* __restrict__ tmp,
        const h8* __restrict__ Xin, h8* __restrict__ Xout,
        const h8* __restrict__ X0, const h8* __restrict__ X1,
        float* __restrict__ out, int nrows) {
    __shared__ int acc[BROWS * LROW];   // 128 x 65 int = 33.3 KB
    int t = threadIdx.x;
    int b = blockIdx.x;

    int4* az = (int4*)acc;
    for (int i = t; i < BROWS * LROW / 4; i += 512) az[i] = make_int4(0, 0, 0, 0);
    __syncthreads();

    int num = cursor1[b];
    if (num > BCAP) num = BCAP;
    const int2* ebase = tmp + (size_t)b * BCAP;

    int g = t >> 3;      // 0..63: one edge per 8-lane group
    int l8 = t & 7;      // 16B chunk of the source row

    int e = g;
    for (; e + 64 < num; e += 128) {
        int2 r0 = ebase[e];
        int2 r1 = ebase[e + 64];
        H8U v0, v1;
        v0.v = Xin[((r0.x >> BUCKET_SHIFT) << 3) + l8];
        v1.v = Xin[((r1.x >> BUCKET_SHIFT) << 3) + l8];
        float w0 = __int_as_float(r0.y) * ACC_SCALE;
        float w1 = __int_as_float(r1.y) * ACC_SCALE;
        int* d0 = &acc[(r0.x & (BROWS - 1)) * LROW + l8 * 8];
        int* d1 = &acc[(r1.x & (BROWS - 1)) * LROW + l8 * 8];
        #pragma unroll
        for (int k = 0; k < 8; k++) atomicAdd(&d0[k], __float2int_rn(w0 * (float)v0.e[k]));
        #pragma unroll
        for (int k = 0; k < 8; k++) atomicAdd(&d1[k], __float2int_rn(w1 * (float)v1.e[k]));
    }
    for (; e < num; e += 64) {
        int2 r0 = ebase[e];
        H8U v0;
        v0.v = Xin[((r0.x >> BUCKET_SHIFT) << 3) + l8];
        float w0 = __int_as_float(r0.y) * ACC_SCALE;
        int* d0 = &acc[(r0.x & (BROWS - 1)) * LROW + l8 * 8];
        #pragma unroll
        for (int k = 0; k < 8; k++) atomicAdd(&d0[k], __float2int_rn(w0 * (float)v0.e[k]));
    }
    __syncthreads();

    // epilogue: 128 rows x 8 chunks of 8 values
    int rowbase = b << BUCKET_SHIFT;
    int rows_here = nrows - rowbase;
    if (rows_here > BROWS) rows_here = BROWS;
    for (int i = t; i < rows_here * 8; i += 512) {
        int r = i >> 3, c8 = i & 7;
        int rowid = rowbase + r;
        const int* src = &acc[r * LROW + c8 * 8];
        if (LAST) {
            h8 x0 = X0[(rowid << 3) + c8];
            h8 v1 = X1[(rowid << 3) + c8];
            h8 v2 = Xin[(rowid << 3) + c8];
            int base = (rowid << 6) + (c8 << 3);
            f4 o0, o1;
            o0.x = 0.25f * ((float)x0[0] + (float)v1[0] + (float)v2[0] + (float)src[0] * ACC_INV);
            o0.y = 0.25f * ((float)x0[1] + (float)v1[1] + (float)v2[1] + (float)src[1] * ACC_INV);
            o0.z = 0.25f * ((float)x0[2] + (float)v1[2] + (float)v2[2] + (float)src[2] * ACC_INV);
            o0.w = 0.25f * ((float)x0[3] + (float)v1[3] + (float)v2[3] + (float)src[3] * ACC_INV);
            o1.x = 0.25f * ((float)x0[4] + (float)v1[4] + (float)v2[4] + (float)src[4] * ACC_INV);
            o1.y = 0.25f * ((float)x0[5] + (float)v1[5] + (float)v2[5] + (float)src[5] * ACC_INV);
            o1.z = 0.25f * ((float)x0[6] + (float)v1[6] + (float)v2[6] + (float)src[6] * ACC_INV);
            o1.w = 0.25f * ((float)x0[7] + (float)v1[7] + (float)v2[7] + (float)src[7] * ACC_INV);
            f4* dst = (f4*)(out + base);
            dst[0] = o0;
            dst[1] = o1;
        } else {
            h8 o;
            #pragma unroll
            for (int k = 0; k < 8; k++) o[k] = (_Float16)((float)src[k] * ACC_INV);
            Xout[(rowid << 3) + c8] = o;
        }
    }
}

extern "C" void kernel_launch(void* const* d_in, const int* in_sizes, int n_in,
                              void* d_out, int out_size, void* d_ws, size_t ws_size,
                              hipStream_t stream) {
    const int* edge_row = (const int*)d_in[0];
    const int* edge_col = (const int*)d_in[1];
    const float* edge_w = (const float*)d_in[2];
    const float* user_emb = (const float*)d_in[3];
    const float* item_emb = (const float*)d_in[4];

    const int E = in_sizes[0];
    const int nu_elems = in_sizes[3];
    const int ni_elems = in_sizes[4];
    const int total = nu_elems + ni_elems;
    const int N = total / EMB;                           // 150000
    const int NBUCK = (N + BROWS - 1) >> BUCKET_SHIFT;   // 1172

    size_t off = 0;
    auto carve = [&](size_t bytes) {
        void* p = (char*)d_ws + off;
        off += (bytes + 255) & ~(size_t)255;
        return p;
    };
    h8*    X0h     = (h8*)carve((size_t)total * 2);
    h8*    X1h     = (h8*)carve((size_t)total * 2);
    h8*    X2h     = (h8*)carve((size_t)total * 2);
    int*   cursor1 = (int*)carve((size_t)NBUCK * 4);
    int2*  tmp     = (int2*)carve((size_t)NBUCK * BCAP * 8);
    (void)ws_size;

    float* out = (float*)d_out;

    const int total8 = total / 8;
    const int s1Blocks = (E + S1_CHUNK - 1) / S1_CHUNK;
    const int convBlocks = (total8 + 511) / 512;

    hipMemsetAsync(cursor1, 0, (size_t)NBUCK * 4, stream);
    s1_convert<<<s1Blocks + convBlocks, 512, 0, stream>>>(
        edge_row, edge_col, edge_w, cursor1, tmp,
        user_emb, item_emb, X0h, nu_elems, total8, E, s1Blocks);

    spmm_bucket<false><<<NBUCK, 512, 0, stream>>>(cursor1, tmp,
                                                  X0h, X1h, nullptr, nullptr,
                                                  nullptr, N);
    spmm_bucket<false><<<NBUCK, 512, 0, stream>>>(cursor1, tmp,
                                                  X1h, X2h, nullptr, nullptr,
                                                  nullptr, N);
    spmm_bucket<true><<<NBUCK, 512, 0, stream>>>(cursor1, tmp,
                                                 X2h, nullptr, X0h, X1h,
                                                 out, N);
}

// Round 13
// 218.915 us; speedup vs baseline: 1.0484x; 1.0484x over previous
//
#include <hip/hip_runtime.h>
#include <hip/hip_bf16.h>

// LightGCN propagation: x = concat(user,item) [150000,64] f32;
// acc = x; 3x { x = A@x (COO spmm, E=1.2M); acc += x }; out = acc/4.
//
// Round 13 = round 11 (int-fixed-point bucket-LDS spmm, scatter2 DELETED,
// unstaged s1) + 4x-unrolled spmm gather loop (32 gathers in flight/wave):
//  1) memset cursor1 (1172 x 4B)
//  2) s1_convert (role-split grid): LDS-rank edges per bucket (row>>7),
//     reserve via atomicAdd(cursor1[b]), write 8B records tmp[b*BCAP+pos]
//     (UNSTAGED: at shift 7 bucket-runs are ~1.75 records < 32B sector,
//     so staging can't coalesce — round 12 proved it regresses);
//     + x0 fp32->fp16 staging.
//  3-5) spmm_bucket x3: block = bucket (128 rows), 512 thr, LDS acc
//     128x65 INT via native ds_add_u32. 8-lane group per edge, 4x-unroll
//     (round 13; was 2x — spmm is gather-LATENCY bound, more MLP).
//     SCALE=2^20 fixed point: quant 5e-7/term vs 2.4e-4 fp16 floor.
//     Layer 3 fuses out = 0.25*(x0h+x1+x2+acc).
//
// POST-MORTEM LOG:
//  - prior session r6: nt-STORES on Xout REGRESSED spmm: evicts L2 lines
//    next layer's gathers need.
//  - round 2: per-edge GLOBAL atomicAdd(+return) = 331us. NEVER.
//  - round 5: FP32 LDS atomicAdd = 435us/layer (CAS retry). INT LDS
//    atomicAdd is native ds_add — round 11 proved <=42us/layer.
//  - round 6: degree-sorted slots REGRESSED: spmm is GATHER-bound
//    (X=19.2MB vs 4MB/XCD L2), not lockstep-issue-bound.
//  - round 9: packed cw + nt-loads REGRESSED: FETCH -8MB, duration
//    UNCHANGED -> gather-LATENCY bound, not BW.
//  - round 10: quarter-split scatter2 +8us: scan amplification.
//  - round 12: staged s1 at shift 7 REGRESSED 44->53us: runs ~1.75 rec
//    < 32B sector -> no coalescing possible; +433K LDS bank conflicts.
//    Scattered-8B-write cost = SECTOR (32B) amplification: 1.2M x 32B
//    = 38MB, matches counters. Staging pays only when runs >= 4 records
//    (shift 9). 
//  - round 11 (218.3us): this structure at 2x unroll. round 7 (214.1):
//    shift-9 staged pipeline — superseded if this round's unroll lands.

#define EMB 64
#define BUCKET_SHIFT 7
#define BROWS (1 << BUCKET_SHIFT)    // 128 rows per bucket
#define LROW 65                      // LDS row stride (65 = 1 mod 32)
#define NBUCK_PAD 1184
#define S1_CHUNK 2048
#define BCAP 1408                    // Poisson(1024): +12 sigma headroom
#define ACC_SCALE 1048576.0f         // 2^20 fixed-point scale
#define ACC_INV (1.0f / 1048576.0f)

typedef _Float16 h8 __attribute__((ext_vector_type(8)));
typedef float f4 __attribute__((ext_vector_type(4)));

union H8U { h8 v; _Float16 e[8]; };

// ---- fused scatter1 + fp32->fp16 convert (role-split grid) ----
__global__ void s1_convert(const int* __restrict__ row, const int* __restrict__ col,
                           const float* __restrict__ w, int* __restrict__ cursor1,
                           int2* __restrict__ tmp,
                           const float* __restrict__ ue, const float* __restrict__ ie,
                           h8* __restrict__ X0h, int nu_elems, int total8,
                           int E, int s1Blocks) {
    int t = threadIdx.x;
    if ((int)blockIdx.x < s1Blocks) {
        __shared__ int lcount[NBUCK_PAD];
        __shared__ int lbase[NBUCK_PAD];
        int c0 = blockIdx.x * S1_CHUNK;
        for (int i = t; i < NBUCK_PAD; i += 512) lcount[i] = 0;
        __syncthreads();
        int pkc[S1_CHUNK / 512];   // (b<<12)|rank
        int cc[S1_CHUNK / 512];
        int rr[S1_CHUNK / 512];
        float ww[S1_CHUNK / 512];
        #pragma unroll
        for (int i = 0; i < S1_CHUNK / 512; i++) {
            int e = c0 + i * 512 + t;
            pkc[i] = -1;
            if (e < E) {
                int r = row[e];
                int b = r >> BUCKET_SHIFT;
                int rank = atomicAdd(&lcount[b], 1);
                pkc[i] = (b << 12) | rank;
                cc[i] = col[e];
                rr[i] = r & (BROWS - 1);
                ww[i] = w[e];
            }
        }
        __syncthreads();
        for (int i = t; i < NBUCK_PAD; i += 512) {
            int c = lcount[i];
            if (c) lbase[i] = atomicAdd(&cursor1[i], c);
        }
        __syncthreads();
        #pragma unroll
        for (int i = 0; i < S1_CHUNK / 512; i++) {
            if (pkc[i] >= 0) {
                int b = pkc[i] >> 12;
                int pos = lbase[b] + (pkc[i] & 4095);
                if (pos < BCAP)   // overflow guard (never triggers at +12 sigma)
                    tmp[(size_t)b * BCAP + pos] =
                        make_int2((cc[i] << BUCKET_SHIFT) | rr[i], __float_as_int(ww[i]));
            }
        }
    } else {
        int g = (blockIdx.x - s1Blocks) * 512 + t;
        if (g >= total8) return;
        int base = g << 3;
        const f4* src = (const f4*)((base < nu_elems) ? (ue + base)
                                                      : (ie + (base - nu_elems)));
        f4 a = src[0], b = src[1];
        h8 o;
        o[0] = (_Float16)a.x; o[1] = (_Float16)a.y; o[2] = (_Float16)a.z; o[3] = (_Float16)a.w;
        o[4] = (_Float16)b.x; o[5] = (_Float16)b.y; o[6] = (_Float16)b.z; o[7] = (_Float16)b.w;
        X0h[g] = o;
    }
}

// ---- spmm: bucket-per-block, INT LDS accumulate, 4x-unrolled gathers ----
// LAST fuses out = 0.25*(x0h + x1 + x2 + acc)
template <bool LAST>
__global__ __launch_bounds__(512) void spmm_bucket(
        const int* __restrict__ cursor1, const int2* __restrict__ tmp,
        const h8* __restrict__ Xin, h8* __restrict__ Xout,
        const h8* __restrict__ X0, const h8* __restrict__ X1,
        float* __restrict__ out, int nrows) {
    __shared__ int acc[BROWS * LROW];   // 128 x 65 int = 33.3 KB
    int t = threadIdx.x;
    int b = blockIdx.x;

    int4* az = (int4*)acc;
    for (int i = t; i < BROWS * LROW / 4; i += 512) az[i] = make_int4(0, 0, 0, 0);
    __syncthreads();

    int num = cursor1[b];
    if (num > BCAP) num = BCAP;
    const int2* ebase = tmp + (size_t)b * BCAP;

    int g = t >> 3;      // 0..63: one edge per 8-lane group
    int l8 = t & 7;      // 16B chunk of the source row

    int e = g;
    for (; e + 192 < num; e += 256) {
        int2 r0 = ebase[e];
        int2 r1 = ebase[e + 64];
        int2 r2 = ebase[e + 128];
        int2 r3 = ebase[e + 192];
        H8U v0, v1, v2, v3;
        v0.v = Xin[((r0.x >> BUCKET_SHIFT) << 3) + l8];
        v1.v = Xin[((r1.x >> BUCKET_SHIFT) << 3) + l8];
        v2.v = Xin[((r2.x >> BUCKET_SHIFT) << 3) + l8];
        v3.v = Xin[((r3.x >> BUCKET_SHIFT) << 3) + l8];
        float w0 = __int_as_float(r0.y) * ACC_SCALE;
        float w1 = __int_as_float(r1.y) * ACC_SCALE;
        float w2 = __int_as_float(r2.y) * ACC_SCALE;
        float w3 = __int_as_float(r3.y) * ACC_SCALE;
        int* d0 = &acc[(r0.x & (BROWS - 1)) * LROW + l8 * 8];
        int* d1 = &acc[(r1.x & (BROWS - 1)) * LROW + l8 * 8];
        int* d2 = &acc[(r2.x & (BROWS - 1)) * LROW + l8 * 8];
        int* d3 = &acc[(r3.x & (BROWS - 1)) * LROW + l8 * 8];
        #pragma unroll
        for (int k = 0; k < 8; k++) atomicAdd(&d0[k], __float2int_rn(w0 * (float)v0.e[k]));
        #pragma unroll
        for (int k = 0; k < 8; k++) atomicAdd(&d1[k], __float2int_rn(w1 * (float)v1.e[k]));
        #pragma unroll
        for (int k = 0; k < 8; k++) atomicAdd(&d2[k], __float2int_rn(w2 * (float)v2.e[k]));
        #pragma unroll
        for (int k = 0; k < 8; k++) atomicAdd(&d3[k], __float2int_rn(w3 * (float)v3.e[k]));
    }
    for (; e + 64 < num; e += 128) {
        int2 r0 = ebase[e];
        int2 r1 = ebase[e + 64];
        H8U v0, v1;
        v0.v = Xin[((r0.x >> BUCKET_SHIFT) << 3) + l8];
        v1.v = Xin[((r1.x >> BUCKET_SHIFT) << 3) + l8];
        float w0 = __int_as_float(r0.y) * ACC_SCALE;
        float w1 = __int_as_float(r1.y) * ACC_SCALE;
        int* d0 = &acc[(r0.x & (BROWS - 1)) * LROW + l8 * 8];
        int* d1 = &acc[(r1.x & (BROWS - 1)) * LROW + l8 * 8];
        #pragma unroll
        for (int k = 0; k < 8; k++) atomicAdd(&d0[k], __float2int_rn(w0 * (float)v0.e[k]));
        #pragma unroll
        for (int k = 0; k < 8; k++) atomicAdd(&d1[k], __float2int_rn(w1 * (float)v1.e[k]));
    }
    for (; e < num; e += 64) {
        int2 r0 = ebase[e];
        H8U v0;
        v0.v = Xin[((r0.x >> BUCKET_SHIFT) << 3) + l8];
        float w0 = __int_as_float(r0.y) * ACC_SCALE;
        int* d0 = &acc[(r0.x & (BROWS - 1)) * LROW + l8 * 8];
        #pragma unroll
        for (int k = 0; k < 8; k++) atomicAdd(&d0[k], __float2int_rn(w0 * (float)v0.e[k]));
    }
    __syncthreads();

    // epilogue: 128 rows x 8 chunks of 8 values
    int rowbase = b << BUCKET_SHIFT;
    int rows_here = nrows - rowbase;
    if (rows_here > BROWS) rows_here = BROWS;
    for (int i = t; i < rows_here * 8; i += 512) {
        int r = i >> 3, c8 = i & 7;
        int rowid = rowbase + r;
        const int* src = &acc[r * LROW + c8 * 8];
        if (LAST) {
            h8 x0 = X0[(rowid << 3) + c8];
            h8 v1 = X1[(rowid << 3) + c8];
            h8 v2 = Xin[(rowid << 3) + c8];
            int base = (rowid << 6) + (c8 << 3);
            f4 o0, o1;
            o0.x = 0.25f * ((float)x0[0] + (float)v1[0] + (float)v2[0] + (float)src[0] * ACC_INV);
            o0.y = 0.25f * ((float)x0[1] + (float)v1[1] + (float)v2[1] + (float)src[1] * ACC_INV);
            o0.z = 0.25f * ((float)x0[2] + (float)v1[2] + (float)v2[2] + (float)src[2] * ACC_INV);
            o0.w = 0.25f * ((float)x0[3] + (float)v1[3] + (float)v2[3] + (float)src[3] * ACC_INV);
            o1.x = 0.25f * ((float)x0[4] + (float)v1[4] + (float)v2[4] + (float)src[4] * ACC_INV);
            o1.y = 0.25f * ((float)x0[5] + (float)v1[5] + (float)v2[5] + (float)src[5] * ACC_INV);
            o1.z = 0.25f * ((float)x0[6] + (float)v1[6] + (float)v2[6] + (float)src[6] * ACC_INV);
            o1.w = 0.25f * ((float)x0[7] + (float)v1[7] + (float)v2[7] + (float)src[7] * ACC_INV);
            f4* dst = (f4*)(out + base);
            dst[0] = o0;
            dst[1] = o1;
        } else {
            h8 o;
            #pragma unroll
            for (int k = 0; k < 8; k++) o[k] = (_Float16)((float)src[k] * ACC_INV);
            Xout[(rowid << 3) + c8] = o;
        }
    }
}

extern "C" void kernel_launch(void* const* d_in, const int* in_sizes, int n_in,
                              void* d_out, int out_size, void* d_ws, size_t ws_size,
                              hipStream_t stream) {
    const int* edge_row = (const int*)d_in[0];
    const int* edge_col = (const int*)d_in[1];
    const float* edge_w = (const float*)d_in[2];
    const float* user_emb = (const float*)d_in[3];
    const float* item_emb = (const float*)d_in[4];

    const int E = in_sizes[0];
    const int nu_elems = in_sizes[3];
    const int ni_elems = in_sizes[4];
    const int total = nu_elems + ni_elems;
    const int N = total / EMB;                           // 150000
    const int NBUCK = (N + BROWS - 1) >> BUCKET_SHIFT;   // 1172

    size_t off = 0;
    auto carve = [&](size_t bytes) {
        void* p = (char*)d_ws + off;
        off += (bytes + 255) & ~(size_t)255;
        return p;
    };
    h8*    X0h     = (h8*)carve((size_t)total * 2);
    h8*    X1h     = (h8*)carve((size_t)total * 2);
    h8*    X2h     = (h8*)carve((size_t)total * 2);
    int*   cursor1 = (int*)carve((size_t)NBUCK * 4);
    int2*  tmp     = (int2*)carve((size_t)NBUCK * BCAP * 8);
    (void)ws_size;

    float* out = (float*)d_out;

    const int total8 = total / 8;
    const int s1Blocks = (E + S1_CHUNK - 1) / S1_CHUNK;
    const int convBlocks = (total8 + 511) / 512;

    hipMemsetAsync(cursor1, 0, (size_t)NBUCK * 4, stream);
    s1_convert<<<s1Blocks + convBlocks, 512, 0, stream>>>(
        edge_row, edge_col, edge_w, cursor1, tmp,
        user_emb, item_emb, X0h, nu_elems, total8, E, s1Blocks);

    spmm_bucket<false><<<NBUCK, 512, 0, stream>>>(cursor1, tmp,
                                                  X0h, X1h, nullptr, nullptr,
                                                  nullptr, N);
    spmm_bucket<false><<<NBUCK, 512, 0, stream>>>(cursor1, tmp,
                                                  X1h, X2h, nullptr, nullptr,
                                                  nullptr, N);
    spmm_bucket<true><<<NBUCK, 512, 0, stream>>>(cursor1, tmp,
                                                 X2h, nullptr, X0h, X1h,
                                                 out, N);
}